// Round 6
// baseline (347.041 us; speedup 1.0000x reference)
//
#include <hip/hip_runtime.h>

typedef float vfloat4 __attribute__((ext_vector_type(4)));
typedef int   vint4   __attribute__((ext_vector_type(4)));

#define BSHIFT 12
#define BSIZE  4096      // DOFs per bucket (16 KB LDS accumulator)
#define G1     1024      // workgroups for hist + fused compute/scatter
#define TPB    256

// u1[bc[k]] = w1[k] * u[bc[k]]
__global__ void scatter_u1_kernel(const float* __restrict__ u,
                                  const float* __restrict__ w1,
                                  const int* __restrict__ bc,
                                  float* __restrict__ u1, int n) {
    int k = blockIdx.x * blockDim.x + threadIdx.x;
    if (k < n) {
        int idx = bc[k];
        u1[idx] = w1[k] * u[idx];
    }
}

// Pass 1: per-workgroup bucket histogram of edof (LDS int atomics only).
// chunk is a multiple of 256 so int4 loads stay aligned.
__global__ void hist_kernel(const int* __restrict__ edof,
                            int* __restrict__ cnt,   // [nb][G1]
                            int total, int nb, int chunk) {
    __shared__ int h[256];
    int wg = blockIdx.x;
    if (threadIdx.x < nb) h[threadIdx.x] = 0;
    __syncthreads();
    int k0 = wg * chunk;
    int k1 = min(k0 + chunk, total);
    for (int k = k0 + threadIdx.x * 4; k < k1; k += TPB * 4) {
        vint4 v = __builtin_nontemporal_load((const vint4*)(edof + k));
        atomicAdd(&h[v.x >> BSHIFT], 1);
        atomicAdd(&h[v.y >> BSHIFT], 1);
        atomicAdd(&h[v.z >> BSHIFT], 1);
        atomicAdd(&h[v.w >> BSHIFT], 1);
    }
    __syncthreads();
    if (threadIdx.x < nb) cnt[threadIdx.x * G1 + wg] = h[threadIdx.x];
}

// Pass 1b: per-bucket exclusive scan over the G1 workgroup counts. 1 wave/bucket.
__global__ void scan_bucket_kernel(const int* __restrict__ cnt,  // [nb][G1]
                                   int* __restrict__ wgoff,      // [nb][G1]
                                   int* __restrict__ btot) {     // [nb]
    int b = blockIdx.x;
    int lane = threadIdx.x;          // 0..63
    const int per = G1 / 64;
    int v[per];
    int s = 0;
    for (int j = 0; j < per; ++j) { v[j] = cnt[b * G1 + lane * per + j]; s += v[j]; }
    int incl = s;
    for (int off = 1; off < 64; off <<= 1) {
        int n = __shfl_up(incl, off, 64);
        if (lane >= off) incl += n;
    }
    int run = incl - s;              // exclusive prefix of this lane's group
    for (int j = 0; j < per; ++j) { wgoff[b * G1 + lane * per + j] = run; run += v[j]; }
    if (lane == 63) btot[b] = incl;
}

// Pass 1c: serial exclusive scan of bucket totals (nb <= 256, trivial).
__global__ void scan_total_kernel(const int* __restrict__ btot,
                                  int* __restrict__ bstart, int nb) {
    if (blockIdx.x == 0 && threadIdx.x == 0) {
        int s = 0;
        for (int b = 0; b < nb; ++b) { bstart[b] = s; s += btot[b]; }
        bstart[nb] = s;
    }
}

// Pass 2 (fused): compute fe AND write (idx,fe) pairs directly to
// bucket-sorted positions. No febuf round-trip, no global atomics.
// chunk must be a multiple of 256 (wave/element alignment for shfl width=8)
// and must MATCH hist_kernel's chunking.
__global__ void compute_fe_scatter_kernel(const float* __restrict__ u1,
                                          const int* __restrict__ edof,
                                          const float* __restrict__ stiff,
                                          const int* __restrict__ wgoff,  // [nb][G1]
                                          const int* __restrict__ bstart,
                                          unsigned long long* __restrict__ pairs,
                                          int total, int nb, int chunk) {
    __shared__ int base[256];
    int wg = blockIdx.x;
    if (threadIdx.x < nb)
        base[threadIdx.x] = bstart[threadIdx.x] + wgoff[threadIdx.x * G1 + wg];
    __syncthreads();
    int k0 = wg * chunk;
    int k1 = min(k0 + chunk, total);
    for (int k = k0 + threadIdx.x; k < k1; k += TPB) {
        int e = k >> 3;
        int i = k & 7;
        int idx = __builtin_nontemporal_load(edof + k);
        float ue = u1[idx];

        const vfloat4* Kr = (const vfloat4*)(stiff + (size_t)e * 64 + (size_t)i * 8);
        vfloat4 ka = __builtin_nontemporal_load(Kr);
        vfloat4 kb = __builtin_nontemporal_load(Kr + 1);

        float fe;
        fe  = ka.x * __shfl(ue, 0, 8);
        fe += ka.y * __shfl(ue, 1, 8);
        fe += ka.z * __shfl(ue, 2, 8);
        fe += ka.w * __shfl(ue, 3, 8);
        fe += kb.x * __shfl(ue, 4, 8);
        fe += kb.y * __shfl(ue, 5, 8);
        fe += kb.z * __shfl(ue, 6, 8);
        fe += kb.w * __shfl(ue, 7, 8);

        int b = idx >> BSHIFT;
        int pos = atomicAdd(&base[b], 1);   // LDS atomic only
        pairs[pos] = ((unsigned long long)(unsigned)idx << 32) | __float_as_uint(fe);
    }
}

// Pass 3: one workgroup per bucket. LDS fp32 accumulate, coalesced store.
// Covers every DOF, so no F memset needed.
__global__ void bucket_reduce_kernel(const unsigned long long* __restrict__ pairs,
                                     const int* __restrict__ bstart,
                                     float* __restrict__ F, int ndof) {
    __shared__ float acc[BSIZE];
    int b = blockIdx.x;
    for (int j = threadIdx.x; j < BSIZE; j += TPB) acc[j] = 0.0f;
    __syncthreads();
    int k0 = bstart[b], k1 = bstart[b + 1];
    for (int k = k0 + threadIdx.x; k < k1; k += TPB) {
        unsigned long long p = pairs[k];
        int idx = (int)(p >> 32);
        float fe = __uint_as_float((unsigned)p);
        atomicAdd(&acc[idx & (BSIZE - 1)], fe);
    }
    __syncthreads();
    int gbase = b << BSHIFT;
    for (int j = threadIdx.x; j < BSIZE; j += TPB) {
        int g = gbase + j;
        if (g < ndof) F[g] = acc[j];
    }
}

// Fallback (fused atomics) if ws too small.
__global__ void elem_assemble_kernel(const float* __restrict__ u1,
                                     const int* __restrict__ edof,
                                     const float* __restrict__ stiff,
                                     float* __restrict__ F, int nelem) {
    int t = blockIdx.x * blockDim.x + threadIdx.x;
    int e = t >> 3;
    if (e >= nelem) return;
    int i = t & 7;
    int idx = __builtin_nontemporal_load(edof + t);
    float ue = u1[idx];
    const vfloat4* Kr = (const vfloat4*)(stiff + (size_t)e * 64 + (size_t)i * 8);
    vfloat4 k0 = __builtin_nontemporal_load(Kr);
    vfloat4 k1 = __builtin_nontemporal_load(Kr + 1);
    float fe;
    fe  = k0.x * __shfl(ue, 0, 8);
    fe += k0.y * __shfl(ue, 1, 8);
    fe += k0.z * __shfl(ue, 2, 8);
    fe += k0.w * __shfl(ue, 3, 8);
    fe += k1.x * __shfl(ue, 4, 8);
    fe += k1.y * __shfl(ue, 5, 8);
    fe += k1.z * __shfl(ue, 6, 8);
    fe += k1.w * __shfl(ue, 7, 8);
    unsafeAtomicAdd(&F[idx], fe);
}

extern "C" void kernel_launch(void* const* d_in, const int* in_sizes, int n_in,
                              void* d_out, int out_size, void* d_ws, size_t ws_size,
                              hipStream_t stream) {
    const float* u     = (const float*)d_in[0];
    const float* w1    = (const float*)d_in[1];
    const int*   bc    = (const int*)d_in[2];
    const int*   edof  = (const int*)d_in[3];
    const float* stiff = (const float*)d_in[4];
    float* F = (float*)d_out;

    int ndof  = in_sizes[0];
    int nbc   = in_sizes[2];
    int total = in_sizes[3];      // NELEM * 8 (multiple of 8)
    int nelem = total / 8;
    int nb    = (ndof + BSIZE - 1) >> BSHIFT;

    // Carve workspace (256 B aligned chunks).
    char* w = (char*)d_ws;
    size_t o = 0;
    auto take = [&](size_t nbytes) -> char* {
        char* p = w + o;
        o += (nbytes + 255) & ~(size_t)255;
        return p;
    };
    float* u1 = (float*)take((size_t)ndof * 4);
    unsigned long long* pairs = (unsigned long long*)take((size_t)total * 8);
    int* cnt    = (int*)take((size_t)nb * G1 * 4);
    int* wgoff  = (int*)take((size_t)nb * G1 * 4);
    int* btot   = (int*)take((size_t)nb * 4);
    int* bstart = (int*)take((size_t)(nb + 1) * 4);

    (void)hipMemsetAsync(u1, 0, (size_t)ndof * sizeof(float), stream);
    scatter_u1_kernel<<<(nbc + TPB - 1) / TPB, TPB, 0, stream>>>(u, w1, bc, u1, nbc);

    if (o <= ws_size && nb <= 256 && total % 8 == 0) {
        // chunk: multiple of 256, identical for hist and fused compute/scatter.
        int chunk = (((total + G1 - 1) / G1) + 255) & ~255;
        hist_kernel<<<G1, TPB, 0, stream>>>(edof, cnt, total, nb, chunk);
        scan_bucket_kernel<<<nb, 64, 0, stream>>>(cnt, wgoff, btot);
        scan_total_kernel<<<1, 64, 0, stream>>>(btot, bstart, nb);
        compute_fe_scatter_kernel<<<G1, TPB, 0, stream>>>(
            u1, edof, stiff, wgoff, bstart, pairs, total, nb, chunk);
        bucket_reduce_kernel<<<nb, TPB, 0, stream>>>(pairs, bstart, F, ndof);
    } else {
        (void)hipMemsetAsync(F, 0, (size_t)ndof * sizeof(float), stream);
        elem_assemble_kernel<<<(total + TPB - 1) / TPB, TPB, 0, stream>>>(
            u1, edof, stiff, F, nelem);
    }
}

// Round 7
// 301.119 us; speedup vs baseline: 1.1525x; 1.1525x over previous
//
#include <hip/hip_runtime.h>

typedef float vfloat4 __attribute__((ext_vector_type(4)));
typedef int   vint4   __attribute__((ext_vector_type(4)));

#define BSHIFT 12
#define BSIZE  4096      // DOFs per bucket (16 KB LDS accumulator)
#define G1     512       // workgroups for hist/scatter passes
#define TPB    256

// u1[bc[k]] = w1[k] * u[bc[k]]
__global__ void scatter_u1_kernel(const float* __restrict__ u,
                                  const float* __restrict__ w1,
                                  const int* __restrict__ bc,
                                  float* __restrict__ u1, int n) {
    int k = blockIdx.x * blockDim.x + threadIdx.x;
    if (k < n) {
        int idx = bc[k];
        u1[idx] = w1[k] * u[idx];
    }
}

// Streaming kernel: 8 threads/element, fe_i = sum_j K[i][j]*ue_j,
// coalesced store to febuf. Kept SEPARATE from the scatter: the 128 MB
// non-temporal K stream would evict the scatter's open pair lines (R6 lesson).
__global__ void compute_fe_kernel(const float* __restrict__ u1,
                                  const int* __restrict__ edof,
                                  const float* __restrict__ stiff,
                                  float* __restrict__ febuf, int nelem) {
    int t = blockIdx.x * blockDim.x + threadIdx.x;
    int e = t >> 3;
    if (e >= nelem) return;
    int i = t & 7;

    int idx = __builtin_nontemporal_load(edof + t);
    float ue = u1[idx];

    const vfloat4* Kr = (const vfloat4*)(stiff + (size_t)e * 64 + (size_t)i * 8);
    vfloat4 k0 = __builtin_nontemporal_load(Kr);
    vfloat4 k1 = __builtin_nontemporal_load(Kr + 1);

    float fe;
    fe  = k0.x * __shfl(ue, 0, 8);
    fe += k0.y * __shfl(ue, 1, 8);
    fe += k0.z * __shfl(ue, 2, 8);
    fe += k0.w * __shfl(ue, 3, 8);
    fe += k1.x * __shfl(ue, 4, 8);
    fe += k1.y * __shfl(ue, 5, 8);
    fe += k1.z * __shfl(ue, 6, 8);
    fe += k1.w * __shfl(ue, 7, 8);

    __builtin_nontemporal_store(fe, febuf + t);
}

// Pass 1: per-workgroup bucket histogram (LDS int atomics, int4 loads).
__global__ void hist_kernel(const int* __restrict__ edof,
                            int* __restrict__ cnt,   // [nb][G1]
                            int total, int nb, int chunk) {
    __shared__ int h[256];
    int wg = blockIdx.x;
    if (threadIdx.x < nb) h[threadIdx.x] = 0;
    __syncthreads();
    int k0 = wg * chunk;
    int k1 = min(k0 + chunk, total);
    for (int k = k0 + threadIdx.x * 4; k < k1; k += TPB * 4) {
        vint4 v = __builtin_nontemporal_load((const vint4*)(edof + k));
        atomicAdd(&h[v.x >> BSHIFT], 1);
        atomicAdd(&h[v.y >> BSHIFT], 1);
        atomicAdd(&h[v.z >> BSHIFT], 1);
        atomicAdd(&h[v.w >> BSHIFT], 1);
    }
    __syncthreads();
    if (threadIdx.x < nb) cnt[threadIdx.x * G1 + wg] = h[threadIdx.x];
}

// Pass 1b: per-bucket exclusive scan over the G1 workgroup counts. 1 wave/bucket.
__global__ void scan_bucket_kernel(const int* __restrict__ cnt,  // [nb][G1]
                                   int* __restrict__ wgoff,      // [nb][G1]
                                   int* __restrict__ btot) {     // [nb]
    int b = blockIdx.x;
    int lane = threadIdx.x;          // 0..63
    const int per = G1 / 64;
    int v[per];
    int s = 0;
    for (int j = 0; j < per; ++j) { v[j] = cnt[b * G1 + lane * per + j]; s += v[j]; }
    int incl = s;
    for (int off = 1; off < 64; off <<= 1) {
        int n = __shfl_up(incl, off, 64);
        if (lane >= off) incl += n;
    }
    int run = incl - s;
    for (int j = 0; j < per; ++j) { wgoff[b * G1 + lane * per + j] = run; run += v[j]; }
    if (lane == 63) btot[b] = incl;
}

// Pass 1c: wave-parallel exclusive scan of bucket totals (nb <= 256).
__global__ void scan_total_kernel(const int* __restrict__ btot,
                                  int* __restrict__ bstart, int nb) {
    int lane = threadIdx.x;          // 64 threads
    int v[4];
    int s = 0;
    for (int j = 0; j < 4; ++j) {
        int i = lane * 4 + j;
        v[j] = (i < nb) ? btot[i] : 0;
        s += v[j];
    }
    int incl = s;
    for (int off = 1; off < 64; off <<= 1) {
        int n = __shfl_up(incl, off, 64);
        if (lane >= off) incl += n;
    }
    int run = incl - s;
    for (int j = 0; j < 4; ++j) {
        int i = lane * 4 + j;
        if (i < nb) bstart[i] = run;
        run += v[j];
    }
    if (lane == 63) bstart[nb] = incl;   // grand total
}

// Pass 2: scatter packed 4B entries into bucket-sorted order.
// entry = (idx_within_bucket << 16) | fp16(fe).  Only LDS atomics for ranks.
__global__ void scatter_pairs_kernel(const int* __restrict__ edof,
                                     const float* __restrict__ febuf,
                                     const int* __restrict__ wgoff, // [nb][G1]
                                     const int* __restrict__ bstart,
                                     unsigned int* __restrict__ pairs,
                                     int total, int nb, int chunk) {
    __shared__ int base[256];
    int wg = blockIdx.x;
    if (threadIdx.x < nb)
        base[threadIdx.x] = bstart[threadIdx.x] + wgoff[threadIdx.x * G1 + wg];
    __syncthreads();
    int k0 = wg * chunk;
    int k1 = min(k0 + chunk, total);
    for (int k = k0 + threadIdx.x * 4; k < k1; k += TPB * 4) {
        vint4   idx = __builtin_nontemporal_load((const vint4*)(edof + k));
        vfloat4 fev = __builtin_nontemporal_load((const vfloat4*)(febuf + k));
        int   ids[4] = {idx.x, idx.y, idx.z, idx.w};
        float fes[4] = {fev.x, fev.y, fev.z, fev.w};
        #pragma unroll
        for (int j = 0; j < 4; ++j) {
            int id = ids[j];
            int b = id >> BSHIFT;
            int pos = atomicAdd(&base[b], 1);
            unsigned short hu = __builtin_bit_cast(unsigned short, (_Float16)fes[j]);
            pairs[pos] = ((unsigned)(id & (BSIZE - 1)) << 16) | (unsigned)hu;
        }
    }
}

// Pass 3: one workgroup per bucket. LDS fp32 accumulate, coalesced store.
// Covers every DOF, so no F memset needed.
__global__ void bucket_reduce_kernel(const unsigned int* __restrict__ pairs,
                                     const int* __restrict__ bstart,
                                     float* __restrict__ F, int ndof) {
    __shared__ float acc[BSIZE];
    int b = blockIdx.x;
    for (int j = threadIdx.x; j < BSIZE; j += TPB) acc[j] = 0.0f;
    __syncthreads();
    int k0 = bstart[b], k1 = bstart[b + 1];
    for (int k = k0 + threadIdx.x; k < k1; k += TPB) {
        unsigned p = pairs[k];
        float fe = (float)__builtin_bit_cast(_Float16, (unsigned short)(p & 0xffffu));
        atomicAdd(&acc[p >> 16], fe);
    }
    __syncthreads();
    int gbase = b << BSHIFT;
    for (int j = threadIdx.x; j < BSIZE; j += TPB) {
        int g = gbase + j;
        if (g < ndof) F[g] = acc[j];
    }
}

// Fallback (fused atomics) if ws too small.
__global__ void elem_assemble_kernel(const float* __restrict__ u1,
                                     const int* __restrict__ edof,
                                     const float* __restrict__ stiff,
                                     float* __restrict__ F, int nelem) {
    int t = blockIdx.x * blockDim.x + threadIdx.x;
    int e = t >> 3;
    if (e >= nelem) return;
    int i = t & 7;
    int idx = __builtin_nontemporal_load(edof + t);
    float ue = u1[idx];
    const vfloat4* Kr = (const vfloat4*)(stiff + (size_t)e * 64 + (size_t)i * 8);
    vfloat4 k0 = __builtin_nontemporal_load(Kr);
    vfloat4 k1 = __builtin_nontemporal_load(Kr + 1);
    float fe;
    fe  = k0.x * __shfl(ue, 0, 8);
    fe += k0.y * __shfl(ue, 1, 8);
    fe += k0.z * __shfl(ue, 2, 8);
    fe += k0.w * __shfl(ue, 3, 8);
    fe += k1.x * __shfl(ue, 4, 8);
    fe += k1.y * __shfl(ue, 5, 8);
    fe += k1.z * __shfl(ue, 6, 8);
    fe += k1.w * __shfl(ue, 7, 8);
    unsafeAtomicAdd(&F[idx], fe);
}

extern "C" void kernel_launch(void* const* d_in, const int* in_sizes, int n_in,
                              void* d_out, int out_size, void* d_ws, size_t ws_size,
                              hipStream_t stream) {
    const float* u     = (const float*)d_in[0];
    const float* w1    = (const float*)d_in[1];
    const int*   bc    = (const int*)d_in[2];
    const int*   edof  = (const int*)d_in[3];
    const float* stiff = (const float*)d_in[4];
    float* F = (float*)d_out;

    int ndof  = in_sizes[0];
    int nbc   = in_sizes[2];
    int total = in_sizes[3];      // NELEM * 8
    int nelem = total / 8;
    int nb    = (ndof + BSIZE - 1) >> BSHIFT;

    // Carve workspace (256 B aligned chunks).
    char* w = (char*)d_ws;
    size_t o = 0;
    auto take = [&](size_t nbytes) -> char* {
        char* p = w + o;
        o += (nbytes + 255) & ~(size_t)255;
        return p;
    };
    float* u1    = (float*)take((size_t)ndof * 4);
    float* febuf = (float*)take((size_t)total * 4);
    unsigned int* pairs = (unsigned int*)take((size_t)total * 4);
    int* cnt    = (int*)take((size_t)nb * G1 * 4);
    int* wgoff  = (int*)take((size_t)nb * G1 * 4);
    int* btot   = (int*)take((size_t)nb * 4);
    int* bstart = (int*)take((size_t)(nb + 1) * 4);

    (void)hipMemsetAsync(u1, 0, (size_t)ndof * sizeof(float), stream);
    scatter_u1_kernel<<<(nbc + TPB - 1) / TPB, TPB, 0, stream>>>(u, w1, bc, u1, nbc);

    if (o <= ws_size && nb <= 256 && total % 8 == 0) {
        // chunk: multiple of 1024 (int4 alignment), identical for hist/scatter.
        int chunk = (((total + G1 - 1) / G1) + 1023) & ~1023;
        hist_kernel<<<G1, TPB, 0, stream>>>(edof, cnt, total, nb, chunk);
        scan_bucket_kernel<<<nb, 64, 0, stream>>>(cnt, wgoff, btot);
        scan_total_kernel<<<1, 64, 0, stream>>>(btot, bstart, nb);
        compute_fe_kernel<<<(total + TPB - 1) / TPB, TPB, 0, stream>>>(
            u1, edof, stiff, febuf, nelem);
        scatter_pairs_kernel<<<G1, TPB, 0, stream>>>(
            edof, febuf, wgoff, bstart, pairs, total, nb, chunk);
        bucket_reduce_kernel<<<nb, TPB, 0, stream>>>(pairs, bstart, F, ndof);
    } else {
        (void)hipMemsetAsync(F, 0, (size_t)ndof * sizeof(float), stream);
        elem_assemble_kernel<<<(total + TPB - 1) / TPB, TPB, 0, stream>>>(
            u1, edof, stiff, F, nelem);
    }
}

// Round 8
// 299.913 us; speedup vs baseline: 1.1571x; 1.0040x over previous
//
#include <hip/hip_runtime.h>

typedef float          vfloat4  __attribute__((ext_vector_type(4)));
typedef int            vint4    __attribute__((ext_vector_type(4)));
typedef unsigned short vushort4 __attribute__((ext_vector_type(4)));

#define BSHIFT 12
#define BSIZE  4096      // DOFs per bucket (16 KB LDS accumulator)
#define G1     512       // workgroups for chunked passes
#define TPB    256

// u1[bc[k]] = w1[k] * u[bc[k]]
__global__ void scatter_u1_kernel(const float* __restrict__ u,
                                  const float* __restrict__ w1,
                                  const int* __restrict__ bc,
                                  float* __restrict__ u1, int n) {
    int k = blockIdx.x * blockDim.x + threadIdx.x;
    if (k < n) {
        int idx = bc[k];
        u1[idx] = w1[k] * u[idx];
    }
}

// Streaming kernel: 8 threads/element, fe_i = sum_j K[i][j]*ue_j,
// fp16 store to febuf16 AND per-WG bucket histogram (LDS atomics only —
// no global scatter, so the R6 K-stream/L2-thrash mechanism doesn't apply).
// Chunked identically to scatter_pairs so cnt[b][wg] matches its chunks.
__global__ void compute_fe_hist_kernel(const float* __restrict__ u1,
                                       const int* __restrict__ edof,
                                       const float* __restrict__ stiff,
                                       unsigned short* __restrict__ febuf16,
                                       int* __restrict__ cnt,  // [nb][G1]
                                       int total, int nb, int chunk) {
    __shared__ int h[256];
    int wg = blockIdx.x;
    if (threadIdx.x < nb) h[threadIdx.x] = 0;
    __syncthreads();
    int k0 = wg * chunk;
    int k1 = min(k0 + chunk, total);
    for (int k = k0 + threadIdx.x; k < k1; k += TPB) {
        int e = k >> 3;
        int i = k & 7;
        int idx = __builtin_nontemporal_load(edof + k);
        float ue = u1[idx];

        const vfloat4* Kr = (const vfloat4*)(stiff + (size_t)e * 64 + (size_t)i * 8);
        vfloat4 ka = __builtin_nontemporal_load(Kr);
        vfloat4 kb = __builtin_nontemporal_load(Kr + 1);

        float fe;
        fe  = ka.x * __shfl(ue, 0, 8);
        fe += ka.y * __shfl(ue, 1, 8);
        fe += ka.z * __shfl(ue, 2, 8);
        fe += ka.w * __shfl(ue, 3, 8);
        fe += kb.x * __shfl(ue, 4, 8);
        fe += kb.y * __shfl(ue, 5, 8);
        fe += kb.z * __shfl(ue, 6, 8);
        fe += kb.w * __shfl(ue, 7, 8);

        unsigned short hu = __builtin_bit_cast(unsigned short, (_Float16)fe);
        __builtin_nontemporal_store(hu, febuf16 + k);
        atomicAdd(&h[idx >> BSHIFT], 1);
    }
    __syncthreads();
    if (threadIdx.x < nb) cnt[threadIdx.x * G1 + wg] = h[threadIdx.x];
}

// Per-bucket exclusive scan over the G1 workgroup counts. 1 wave/bucket.
__global__ void scan_bucket_kernel(const int* __restrict__ cnt,  // [nb][G1]
                                   int* __restrict__ wgoff,      // [nb][G1]
                                   int* __restrict__ btot) {     // [nb]
    int b = blockIdx.x;
    int lane = threadIdx.x;          // 0..63
    const int per = G1 / 64;
    int v[per];
    int s = 0;
    for (int j = 0; j < per; ++j) { v[j] = cnt[b * G1 + lane * per + j]; s += v[j]; }
    int incl = s;
    for (int off = 1; off < 64; off <<= 1) {
        int n = __shfl_up(incl, off, 64);
        if (lane >= off) incl += n;
    }
    int run = incl - s;
    for (int j = 0; j < per; ++j) { wgoff[b * G1 + lane * per + j] = run; run += v[j]; }
    if (lane == 63) btot[b] = incl;
}

// Wave-parallel exclusive scan of bucket totals (nb <= 256).
__global__ void scan_total_kernel(const int* __restrict__ btot,
                                  int* __restrict__ bstart, int nb) {
    int lane = threadIdx.x;          // 64 threads
    int v[4];
    int s = 0;
    for (int j = 0; j < 4; ++j) {
        int i = lane * 4 + j;
        v[j] = (i < nb) ? btot[i] : 0;
        s += v[j];
    }
    int incl = s;
    for (int off = 1; off < 64; off <<= 1) {
        int n = __shfl_up(incl, off, 64);
        if (lane >= off) incl += n;
    }
    int run = incl - s;
    for (int j = 0; j < 4; ++j) {
        int i = lane * 4 + j;
        if (i < nb) bstart[i] = run;
        run += v[j];
    }
    if (lane == 63) bstart[nb] = incl;   // grand total
}

// Scatter packed 4B entries into bucket-sorted order.
// entry = (idx_within_bucket << 16) | fp16(fe). Only LDS atomics for ranks.
// Chunking MUST match compute_fe_hist_kernel.
__global__ void scatter_pairs_kernel(const int* __restrict__ edof,
                                     const unsigned short* __restrict__ febuf16,
                                     const int* __restrict__ wgoff, // [nb][G1]
                                     const int* __restrict__ bstart,
                                     unsigned int* __restrict__ pairs,
                                     int total, int nb, int chunk) {
    __shared__ int base[256];
    int wg = blockIdx.x;
    if (threadIdx.x < nb)
        base[threadIdx.x] = bstart[threadIdx.x] + wgoff[threadIdx.x * G1 + wg];
    __syncthreads();
    int k0 = wg * chunk;
    int k1 = min(k0 + chunk, total);
    for (int k = k0 + threadIdx.x * 4; k < k1; k += TPB * 4) {
        vint4    idx = __builtin_nontemporal_load((const vint4*)(edof + k));
        vushort4 hv  = __builtin_nontemporal_load((const vushort4*)(febuf16 + k));
        int      ids[4] = {idx.x, idx.y, idx.z, idx.w};
        unsigned hus[4] = {hv.x, hv.y, hv.z, hv.w};
        #pragma unroll
        for (int j = 0; j < 4; ++j) {
            int id = ids[j];
            int b = id >> BSHIFT;
            int pos = atomicAdd(&base[b], 1);
            pairs[pos] = ((unsigned)(id & (BSIZE - 1)) << 16) | hus[j];
        }
    }
}

// One workgroup per bucket. LDS fp32 accumulate, coalesced store.
// Covers every DOF, so no F memset needed.
__global__ void bucket_reduce_kernel(const unsigned int* __restrict__ pairs,
                                     const int* __restrict__ bstart,
                                     float* __restrict__ F, int ndof) {
    __shared__ float acc[BSIZE];
    int b = blockIdx.x;
    for (int j = threadIdx.x; j < BSIZE; j += 512) acc[j] = 0.0f;
    __syncthreads();
    int k0 = bstart[b], k1 = bstart[b + 1];
    for (int k = k0 + threadIdx.x; k < k1; k += 512) {
        unsigned p = pairs[k];
        float fe = (float)__builtin_bit_cast(_Float16, (unsigned short)(p & 0xffffu));
        atomicAdd(&acc[p >> 16], fe);
    }
    __syncthreads();
    int gbase = b << BSHIFT;
    for (int j = threadIdx.x; j < BSIZE; j += 512) {
        int g = gbase + j;
        if (g < ndof) F[g] = acc[j];
    }
}

// Fallback (fused atomics) if ws too small.
__global__ void elem_assemble_kernel(const float* __restrict__ u1,
                                     const int* __restrict__ edof,
                                     const float* __restrict__ stiff,
                                     float* __restrict__ F, int nelem) {
    int t = blockIdx.x * blockDim.x + threadIdx.x;
    int e = t >> 3;
    if (e >= nelem) return;
    int i = t & 7;
    int idx = __builtin_nontemporal_load(edof + t);
    float ue = u1[idx];
    const vfloat4* Kr = (const vfloat4*)(stiff + (size_t)e * 64 + (size_t)i * 8);
    vfloat4 k0 = __builtin_nontemporal_load(Kr);
    vfloat4 k1 = __builtin_nontemporal_load(Kr + 1);
    float fe;
    fe  = k0.x * __shfl(ue, 0, 8);
    fe += k0.y * __shfl(ue, 1, 8);
    fe += k0.z * __shfl(ue, 2, 8);
    fe += k0.w * __shfl(ue, 3, 8);
    fe += k1.x * __shfl(ue, 4, 8);
    fe += k1.y * __shfl(ue, 5, 8);
    fe += k1.z * __shfl(ue, 6, 8);
    fe += k1.w * __shfl(ue, 7, 8);
    unsafeAtomicAdd(&F[idx], fe);
}

extern "C" void kernel_launch(void* const* d_in, const int* in_sizes, int n_in,
                              void* d_out, int out_size, void* d_ws, size_t ws_size,
                              hipStream_t stream) {
    const float* u     = (const float*)d_in[0];
    const float* w1    = (const float*)d_in[1];
    const int*   bc    = (const int*)d_in[2];
    const int*   edof  = (const int*)d_in[3];
    const float* stiff = (const float*)d_in[4];
    float* F = (float*)d_out;

    int ndof  = in_sizes[0];
    int nbc   = in_sizes[2];
    int total = in_sizes[3];      // NELEM * 8
    int nelem = total / 8;
    int nb    = (ndof + BSIZE - 1) >> BSHIFT;

    // Carve workspace (256 B aligned chunks).
    char* w = (char*)d_ws;
    size_t o = 0;
    auto take = [&](size_t nbytes) -> char* {
        char* p = w + o;
        o += (nbytes + 255) & ~(size_t)255;
        return p;
    };
    float* u1 = (float*)take((size_t)ndof * 4);
    unsigned short* febuf16 = (unsigned short*)take((size_t)total * 2);
    unsigned int* pairs = (unsigned int*)take((size_t)total * 4);
    int* cnt    = (int*)take((size_t)nb * G1 * 4);
    int* wgoff  = (int*)take((size_t)nb * G1 * 4);
    int* btot   = (int*)take((size_t)nb * 4);
    int* bstart = (int*)take((size_t)(nb + 1) * 4);

    (void)hipMemsetAsync(u1, 0, (size_t)ndof * sizeof(float), stream);
    scatter_u1_kernel<<<(nbc + TPB - 1) / TPB, TPB, 0, stream>>>(u, w1, bc, u1, nbc);

    if (o <= ws_size && nb <= 256 && total % 8 == 0) {
        // chunk: multiple of 1024 (int4 stride in scatter), shared by both
        // chunked kernels so cnt/wgoff line up.
        int chunk = (((total + G1 - 1) / G1) + 1023) & ~1023;
        compute_fe_hist_kernel<<<G1, TPB, 0, stream>>>(
            u1, edof, stiff, febuf16, cnt, total, nb, chunk);
        scan_bucket_kernel<<<nb, 64, 0, stream>>>(cnt, wgoff, btot);
        scan_total_kernel<<<1, 64, 0, stream>>>(btot, bstart, nb);
        scatter_pairs_kernel<<<G1, TPB, 0, stream>>>(
            edof, febuf16, wgoff, bstart, pairs, total, nb, chunk);
        bucket_reduce_kernel<<<nb, 512, 0, stream>>>(pairs, bstart, F, ndof);
    } else {
        (void)hipMemsetAsync(F, 0, (size_t)ndof * sizeof(float), stream);
        elem_assemble_kernel<<<(total + TPB - 1) / TPB, TPB, 0, stream>>>(
            u1, edof, stiff, F, nelem);
    }
}

// Round 9
// 287.794 us; speedup vs baseline: 1.2059x; 1.0421x over previous
//
#include <hip/hip_runtime.h>

typedef float          vfloat4  __attribute__((ext_vector_type(4)));
typedef int            vint4    __attribute__((ext_vector_type(4)));
typedef unsigned short vushort4 __attribute__((ext_vector_type(4)));

#define BSHIFT 12
#define BSIZE  4096      // DOFs per bucket (16 KB LDS accumulator)
#define G1     512       // workgroups for chunked passes (keeps >=128B runs/bucket)
#define TPBC   1024      // threads per WG for chunked passes: 512*16 waves = 100% occ
#define TPB    256

// u1[bc[k]] = w1[k] * u[bc[k]]
__global__ void scatter_u1_kernel(const float* __restrict__ u,
                                  const float* __restrict__ w1,
                                  const int* __restrict__ bc,
                                  float* __restrict__ u1, int n) {
    int k = blockIdx.x * blockDim.x + threadIdx.x;
    if (k < n) {
        int idx = bc[k];
        u1[idx] = w1[k] * u[idx];
    }
}

// Streaming kernel: 8 threads/element, fe_i = sum_j K[i][j]*ue_j,
// fp16 store to febuf16 AND per-WG bucket histogram (LDS atomics only).
// Chunked identically to scatter_pairs so cnt[b][wg] matches its chunks.
// TPBC=1024: 16 waves/WG, 2 WGs/CU -> full wave-slot occupancy to hide the
// random u1 gather latency (R8 lesson: G1*TPB/64 waves was only 25%).
__global__ void compute_fe_hist_kernel(const float* __restrict__ u1,
                                       const int* __restrict__ edof,
                                       const float* __restrict__ stiff,
                                       unsigned short* __restrict__ febuf16,
                                       int* __restrict__ cnt,  // [nb][G1]
                                       int total, int nb, int chunk) {
    __shared__ int h[256];
    int wg = blockIdx.x;
    if (threadIdx.x < nb) h[threadIdx.x] = 0;
    __syncthreads();
    int k0 = wg * chunk;
    int k1 = min(k0 + chunk, total);
    for (int k = k0 + threadIdx.x; k < k1; k += TPBC) {
        int e = k >> 3;
        int i = k & 7;
        int idx = __builtin_nontemporal_load(edof + k);
        float ue = u1[idx];

        const vfloat4* Kr = (const vfloat4*)(stiff + (size_t)e * 64 + (size_t)i * 8);
        vfloat4 ka = __builtin_nontemporal_load(Kr);
        vfloat4 kb = __builtin_nontemporal_load(Kr + 1);

        float fe;
        fe  = ka.x * __shfl(ue, 0, 8);
        fe += ka.y * __shfl(ue, 1, 8);
        fe += ka.z * __shfl(ue, 2, 8);
        fe += ka.w * __shfl(ue, 3, 8);
        fe += kb.x * __shfl(ue, 4, 8);
        fe += kb.y * __shfl(ue, 5, 8);
        fe += kb.z * __shfl(ue, 6, 8);
        fe += kb.w * __shfl(ue, 7, 8);

        unsigned short hu = __builtin_bit_cast(unsigned short, (_Float16)fe);
        __builtin_nontemporal_store(hu, febuf16 + k);
        atomicAdd(&h[idx >> BSHIFT], 1);
    }
    __syncthreads();
    if (threadIdx.x < nb) cnt[threadIdx.x * G1 + wg] = h[threadIdx.x];
}

// Per-bucket exclusive scan over the G1 workgroup counts. 1 wave/bucket.
__global__ void scan_bucket_kernel(const int* __restrict__ cnt,  // [nb][G1]
                                   int* __restrict__ wgoff,      // [nb][G1]
                                   int* __restrict__ btot) {     // [nb]
    int b = blockIdx.x;
    int lane = threadIdx.x;          // 0..63
    const int per = G1 / 64;
    int v[per];
    int s = 0;
    for (int j = 0; j < per; ++j) { v[j] = cnt[b * G1 + lane * per + j]; s += v[j]; }
    int incl = s;
    for (int off = 1; off < 64; off <<= 1) {
        int n = __shfl_up(incl, off, 64);
        if (lane >= off) incl += n;
    }
    int run = incl - s;
    for (int j = 0; j < per; ++j) { wgoff[b * G1 + lane * per + j] = run; run += v[j]; }
    if (lane == 63) btot[b] = incl;
}

// Wave-parallel exclusive scan of bucket totals (nb <= 256).
__global__ void scan_total_kernel(const int* __restrict__ btot,
                                  int* __restrict__ bstart, int nb) {
    int lane = threadIdx.x;          // 64 threads
    int v[4];
    int s = 0;
    for (int j = 0; j < 4; ++j) {
        int i = lane * 4 + j;
        v[j] = (i < nb) ? btot[i] : 0;
        s += v[j];
    }
    int incl = s;
    for (int off = 1; off < 64; off <<= 1) {
        int n = __shfl_up(incl, off, 64);
        if (lane >= off) incl += n;
    }
    int run = incl - s;
    for (int j = 0; j < 4; ++j) {
        int i = lane * 4 + j;
        if (i < nb) bstart[i] = run;
        run += v[j];
    }
    if (lane == 63) bstart[nb] = incl;   // grand total
}

// Scatter packed 4B entries into bucket-sorted order.
// entry = (idx_within_bucket << 16) | fp16(fe). Only LDS atomics for ranks.
// Chunking MUST match compute_fe_hist_kernel. TPBC=1024 for occupancy.
__global__ void scatter_pairs_kernel(const int* __restrict__ edof,
                                     const unsigned short* __restrict__ febuf16,
                                     const int* __restrict__ wgoff, // [nb][G1]
                                     const int* __restrict__ bstart,
                                     unsigned int* __restrict__ pairs,
                                     int total, int nb, int chunk) {
    __shared__ int base[256];
    int wg = blockIdx.x;
    if (threadIdx.x < nb)
        base[threadIdx.x] = bstart[threadIdx.x] + wgoff[threadIdx.x * G1 + wg];
    __syncthreads();
    int k0 = wg * chunk;
    int k1 = min(k0 + chunk, total);
    for (int k = k0 + threadIdx.x * 4; k < k1; k += TPBC * 4) {
        vint4    idx = __builtin_nontemporal_load((const vint4*)(edof + k));
        vushort4 hv  = __builtin_nontemporal_load((const vushort4*)(febuf16 + k));
        int      ids[4] = {idx.x, idx.y, idx.z, idx.w};
        unsigned hus[4] = {hv.x, hv.y, hv.z, hv.w};
        #pragma unroll
        for (int j = 0; j < 4; ++j) {
            int id = ids[j];
            int b = id >> BSHIFT;
            int pos = atomicAdd(&base[b], 1);
            pairs[pos] = ((unsigned)(id & (BSIZE - 1)) << 16) | hus[j];
        }
    }
}

// One workgroup per bucket. LDS fp32 accumulate, coalesced store.
// Covers every DOF, so no F memset needed.
__global__ void bucket_reduce_kernel(const unsigned int* __restrict__ pairs,
                                     const int* __restrict__ bstart,
                                     float* __restrict__ F, int ndof) {
    __shared__ float acc[BSIZE];
    int b = blockIdx.x;
    for (int j = threadIdx.x; j < BSIZE; j += 512) acc[j] = 0.0f;
    __syncthreads();
    int k0 = bstart[b], k1 = bstart[b + 1];
    for (int k = k0 + threadIdx.x; k < k1; k += 512) {
        unsigned p = pairs[k];
        float fe = (float)__builtin_bit_cast(_Float16, (unsigned short)(p & 0xffffu));
        atomicAdd(&acc[p >> 16], fe);
    }
    __syncthreads();
    int gbase = b << BSHIFT;
    for (int j = threadIdx.x; j < BSIZE; j += 512) {
        int g = gbase + j;
        if (g < ndof) F[g] = acc[j];
    }
}

// Fallback (fused atomics) if ws too small.
__global__ void elem_assemble_kernel(const float* __restrict__ u1,
                                     const int* __restrict__ edof,
                                     const float* __restrict__ stiff,
                                     float* __restrict__ F, int nelem) {
    int t = blockIdx.x * blockDim.x + threadIdx.x;
    int e = t >> 3;
    if (e >= nelem) return;
    int i = t & 7;
    int idx = __builtin_nontemporal_load(edof + t);
    float ue = u1[idx];
    const vfloat4* Kr = (const vfloat4*)(stiff + (size_t)e * 64 + (size_t)i * 8);
    vfloat4 k0 = __builtin_nontemporal_load(Kr);
    vfloat4 k1 = __builtin_nontemporal_load(Kr + 1);
    float fe;
    fe  = k0.x * __shfl(ue, 0, 8);
    fe += k0.y * __shfl(ue, 1, 8);
    fe += k0.z * __shfl(ue, 2, 8);
    fe += k0.w * __shfl(ue, 3, 8);
    fe += k1.x * __shfl(ue, 4, 8);
    fe += k1.y * __shfl(ue, 5, 8);
    fe += k1.z * __shfl(ue, 6, 8);
    fe += k1.w * __shfl(ue, 7, 8);
    unsafeAtomicAdd(&F[idx], fe);
}

extern "C" void kernel_launch(void* const* d_in, const int* in_sizes, int n_in,
                              void* d_out, int out_size, void* d_ws, size_t ws_size,
                              hipStream_t stream) {
    const float* u     = (const float*)d_in[0];
    const float* w1    = (const float*)d_in[1];
    const int*   bc    = (const int*)d_in[2];
    const int*   edof  = (const int*)d_in[3];
    const float* stiff = (const float*)d_in[4];
    float* F = (float*)d_out;

    int ndof  = in_sizes[0];
    int nbc   = in_sizes[2];
    int total = in_sizes[3];      // NELEM * 8
    int nelem = total / 8;
    int nb    = (ndof + BSIZE - 1) >> BSHIFT;

    // Carve workspace (256 B aligned chunks).
    char* w = (char*)d_ws;
    size_t o = 0;
    auto take = [&](size_t nbytes) -> char* {
        char* p = w + o;
        o += (nbytes + 255) & ~(size_t)255;
        return p;
    };
    float* u1 = (float*)take((size_t)ndof * 4);
    unsigned short* febuf16 = (unsigned short*)take((size_t)total * 2);
    unsigned int* pairs = (unsigned int*)take((size_t)total * 4);
    int* cnt    = (int*)take((size_t)nb * G1 * 4);
    int* wgoff  = (int*)take((size_t)nb * G1 * 4);
    int* btot   = (int*)take((size_t)nb * 4);
    int* bstart = (int*)take((size_t)(nb + 1) * 4);

    (void)hipMemsetAsync(u1, 0, (size_t)ndof * sizeof(float), stream);
    scatter_u1_kernel<<<(nbc + TPB - 1) / TPB, TPB, 0, stream>>>(u, w1, bc, u1, nbc);

    if (o <= ws_size && nb <= 256 && total % 8 == 0) {
        // chunk: multiple of TPBC*4 (int4 stride alignment in scatter),
        // shared by both chunked kernels so cnt/wgoff line up.
        int chunk = (((total + G1 - 1) / G1) + TPBC * 4 - 1) & ~(TPBC * 4 - 1);
        compute_fe_hist_kernel<<<G1, TPBC, 0, stream>>>(
            u1, edof, stiff, febuf16, cnt, total, nb, chunk);
        scan_bucket_kernel<<<nb, 64, 0, stream>>>(cnt, wgoff, btot);
        scan_total_kernel<<<1, 64, 0, stream>>>(btot, bstart, nb);
        scatter_pairs_kernel<<<G1, TPBC, 0, stream>>>(
            edof, febuf16, wgoff, bstart, pairs, total, nb, chunk);
        bucket_reduce_kernel<<<nb, 512, 0, stream>>>(pairs, bstart, F, ndof);
    } else {
        (void)hipMemsetAsync(F, 0, (size_t)ndof * sizeof(float), stream);
        elem_assemble_kernel<<<(total + TPB - 1) / TPB, TPB, 0, stream>>>(
            u1, edof, stiff, F, nelem);
    }
}